// Round 8
// baseline (523.940 us; speedup 1.0000x reference)
//
#include <hip/hip_runtime.h>

// Problem constants: B=2, S=2048, D=1024, H=16, HD=64
#define S_LEN 2048
#define NH 16
#define HD 64
#define DMODEL 1024

typedef __bf16 bf16x8 __attribute__((ext_vector_type(8)));
typedef float floatx4 __attribute__((ext_vector_type(4)));
typedef short short8 __attribute__((ext_vector_type(8)));

__device__ inline unsigned short f2bf(float f) {
    union { float f; unsigned u; } v; v.f = f;
    unsigned u = v.u;
    unsigned r = (u + 0x7FFFu + ((u >> 16) & 1u)) >> 16;  // RNE
    return (unsigned short)r;
}

// pack two fp32 -> bf16x2 by truncation: one v_perm_b32.
__device__ __forceinline__ unsigned pkhi(float lo, float hi) {
    union { float f; unsigned u; } a, b;
    a.f = lo; b.f = hi;
    return __builtin_amdgcn_perm(b.u, a.u, 0x07060302u);
}

__device__ __forceinline__ void gload_lds16(const void* g, void* l) {
    __builtin_amdgcn_global_load_lds(
        (const __attribute__((address_space(1))) unsigned int*)g,
        (__attribute__((address_space(3))) unsigned int*)l, 16, 0, 0);
}

// Swizzled blocked LDS layouts (16B units). Both staging writes and b128 frag
// reads enumerate to exactly 2 lanes/bank per phase -> free (m136).
#define SWZ(kch, row)    (((kch) * 64  + ((row) ^ ((kch) << 2))) * 8)   // 64-row tiles
#define SWZ128(kch, row) (((kch) * 128 + ((row) ^ ((kch) << 2))) * 8)   // 128-row tiles

// ---------------------------------------------------------------------------
// K1: qkv = x @ w_qkv^T + b_qkv, fused RoPE + scatter.
// 128x128 tile, BK=32, 4 waves 2x2 (16 MFMA/wave/step); fp32 direct loads with
// register prefetch; pkhi truncation pack; swizzled conflict-free LDS.
//  q -> [bh][s][hd] row-major, PRE-SCALED by 1/sqrt(HD)=0.125 (exact)
//  k -> blocked [bh][hdblk(8)][s(2048)][8]   (RoPE applied)
//  v -> blocked [bh][sblk(256)][hd(64)][8]   (direct packed uint2 stores)
// ---------------------------------------------------------------------------
__global__ __launch_bounds__(256) void qkv_rope_kernel(
    const float* __restrict__ x, const float* __restrict__ w,
    const float* __restrict__ bias, const float* __restrict__ freqs,
    unsigned short* __restrict__ qb, unsigned short* __restrict__ kb,
    unsigned short* __restrict__ vb)
{
    __shared__ __align__(16) unsigned short As[4096];   // 128 x 32 bf16, swizzled
    __shared__ __align__(16) unsigned short Bs[4096];

    const int t = threadIdx.x;
    const int wv = t >> 6, lane = t & 63, quad = lane >> 4, l16 = lane & 15;
    const int mbase = (blockIdx.x / 24) * 128;
    const int nbase = (blockIdx.x % 24) * 128;
    const int wm = wv >> 1, wn = wv & 1;

    floatx4 acc[4][4];
    for (int i = 0; i < 4; i++)
        for (int j = 0; j < 4; j++)
            for (int r = 0; r < 4; r++) acc[i][j][r] = 0.f;

    const int srow = t >> 1;          // 0..127
    const int kh   = t & 1;           // 16-elem half of the 32-K tile
    const int kcA  = kh * 2;          // chunks kcA, kcA+1
    const int w0 = SWZ128(kcA, srow), w1 = SWZ128(kcA + 1, srow);
    int aroff[4], broff[4];
    #pragma unroll
    for (int mf = 0; mf < 4; mf++) aroff[mf] = SWZ128(quad, wm * 64 + mf * 16 + l16);
    #pragma unroll
    for (int nf = 0; nf < 4; nf++) broff[nf] = SWZ128(quad, wn * 64 + nf * 16 + l16);

    const float* ap = x + (size_t)(mbase + srow) * DMODEL + kh * 16;
    const float* bp = w + (size_t)(nbase + srow) * DMODEL + kh * 16;
    float4 a0 = *(const float4*)ap,       a1 = *(const float4*)(ap + 4);
    float4 a2 = *(const float4*)(ap + 8), a3 = *(const float4*)(ap + 12);
    float4 b0 = *(const float4*)bp,       b1 = *(const float4*)(bp + 4);
    float4 b2 = *(const float4*)(bp + 8), b3 = *(const float4*)(bp + 12);

    for (int k0 = 0; k0 < DMODEL; k0 += 32) {
        uint4 av0, av1, bv0, bv1;
        av0.x = pkhi(a0.x, a0.y); av0.y = pkhi(a0.z, a0.w);
        av0.z = pkhi(a1.x, a1.y); av0.w = pkhi(a1.z, a1.w);
        av1.x = pkhi(a2.x, a2.y); av1.y = pkhi(a2.z, a2.w);
        av1.z = pkhi(a3.x, a3.y); av1.w = pkhi(a3.z, a3.w);
        bv0.x = pkhi(b0.x, b0.y); bv0.y = pkhi(b0.z, b0.w);
        bv0.z = pkhi(b1.x, b1.y); bv0.w = pkhi(b1.z, b1.w);
        bv1.x = pkhi(b2.x, b2.y); bv1.y = pkhi(b2.z, b2.w);
        bv1.z = pkhi(b3.x, b3.y); bv1.w = pkhi(b3.z, b3.w);
        __syncthreads();                       // prev iter's frag reads done
        *(uint4*)&As[w0] = av0;  *(uint4*)&As[w1] = av1;
        *(uint4*)&Bs[w0] = bv0;  *(uint4*)&Bs[w1] = bv1;
        if (k0 + 32 < DMODEL) {                // register prefetch of next K-tile
            const float* ap2 = ap + k0 + 32;
            a0 = *(const float4*)ap2;       a1 = *(const float4*)(ap2 + 4);
            a2 = *(const float4*)(ap2 + 8); a3 = *(const float4*)(ap2 + 12);
            const float* bp2 = bp + k0 + 32;
            b0 = *(const float4*)bp2;       b1 = *(const float4*)(bp2 + 4);
            b2 = *(const float4*)(bp2 + 8); b3 = *(const float4*)(bp2 + 12);
        }
        __syncthreads();                       // staging visible
        bf16x8 af[4], bfr[4];
        #pragma unroll
        for (int mf = 0; mf < 4; mf++) af[mf] = *(const bf16x8*)&As[aroff[mf]];
        #pragma unroll
        for (int nf = 0; nf < 4; nf++) bfr[nf] = *(const bf16x8*)&Bs[broff[nf]];
        #pragma unroll
        for (int mf = 0; mf < 4; mf++)
            #pragma unroll
            for (int nf = 0; nf < 4; nf++)
                acc[mf][nf] = __builtin_amdgcn_mfma_f32_16x16x32_bf16(af[mf], bfr[nf], acc[mf][nf], 0, 0, 0);
    }

    // ---- epilogue (R5-verified): wave quadrant = 64m x 64n; 64-col quad = one head
    const int nq = nbase + wn * 64;          // multiple of 64
    const int part = nq >> 10;               // 0=q 1=k 2=v (wave-uniform)
    const int h    = (nq & 1023) >> 6;
    const int mq   = mbase + wm * 64;
    const int bidx = mq >> 11;
    const int s0   = mq & 2047;
    const size_t bh = (size_t)bidx * NH + h;

    if (part == 2) {
        #pragma unroll
        for (int mf = 0; mf < 4; mf++) {
            const int s = s0 + mf * 16 + quad * 4;
            const int sblk = s >> 3;
            const int off  = (quad & 1) * 4;
            #pragma unroll
            for (int nf = 0; nf < 4; nf++) {
                const int hd = nf * 16 + l16;
                const float bvv = bias[nq + hd];
                union { unsigned short s4[4]; uint2 u; } pk;
                #pragma unroll
                for (int r = 0; r < 4; r++) pk.s4[r] = f2bf(acc[mf][nf][r] + bvv);
                *(uint2*)&vb[(((bh * 256) + sblk) * 64 + hd) * 8 + off] = pk.u;
            }
        }
    } else {
        #pragma unroll
        for (int nf = 0; nf < 4; nf++) {
            const int hd = nf * 16 + l16;
            const float bvv = bias[nq + hd];
            const int i = hd >> 1;
            #pragma unroll
            for (int mf = 0; mf < 4; mf++) {
                #pragma unroll
                for (int r = 0; r < 4; r++) {
                    const int s = s0 + mf * 16 + quad * 4 + r;
                    float val = acc[mf][nf][r] + bvv;
                    float other = __shfl_xor(val, 1, 64);   // RoPE pair = adjacent hd
                    const float f = freqs[s * 32 + i];
                    const float cc = cosf(f), sn = sinf(f);
                    float outv;
                    if ((hd & 1) == 0) outv = val * cc - other * sn;
                    else               outv = other * sn + val * cc;
                    if (part == 0) {
                        outv *= 0.125f;                     // fold 1/sqrt(HD), exact
                        qb[(bh * S_LEN + s) * HD + hd] = f2bf(outv);
                    } else {
                        kb[((bh * 8 + (hd >> 3)) * (size_t)S_LEN + s) * 8 + (hd & 7)] = f2bf(outv);
                    }
                }
            }
        }
    }
}

// ---------------------------------------------------------------------------
// K2: causal flash attention (R4/R6 winner, unchanged). No-max softmax;
// transposed QK; barrier-free P roundtrip; 1 barrier per tile; grid 1024.
// ---------------------------------------------------------------------------
__global__ __launch_bounds__(256, 4) void attn_kernel(
    const unsigned short* __restrict__ qb, const unsigned short* __restrict__ kb,
    const unsigned short* __restrict__ vbk, unsigned short* __restrict__ ao)
{
    __shared__ __align__(16) unsigned short Ks[8 * 512];
    __shared__ __align__(16) unsigned short Vt[8 * 512];
    __shared__ __align__(16) unsigned short Pw[4][16 * 72];

    const int t = threadIdx.x;
    const int wv = t >> 6, lane = t & 63, quad = lane >> 4, l16 = lane & 15;
    const int qt   = blockIdx.x >> 5;
    const int bhid = blockIdx.x & 31;
    const int h = bhid & 15, b = bhid >> 4;
    const size_t bh = (size_t)b * NH + h;
    const unsigned short* qg  = qb + bh * S_LEN * HD;
    const unsigned short* kgB = kb + bh * 8 * S_LEN * 8;
    const unsigned short* vgB = vbk + bh * 256 * 64 * 8;

    bf16x8 qf[2];
    {
        const unsigned short* q0 = qg + (size_t)(qt * 64 + wv * 16 + l16) * HD;
        qf[0] = *(const bf16x8*)&q0[quad * 8];
        qf[1] = *(const bf16x8*)&q0[32 + quad * 8];
    }

    bf16x8 ones;
    {
        union { short8 s; bf16x8 v; } o;
        for (int j = 0; j < 8; j++) o.s[j] = 0x3F80;
        ones = o.v;
    }

    floatx4 lfr = {0.f, 0.f, 0.f, 0.f};
    floatx4 Ofr[4];
    for (int nt = 0; nt < 4; nt++)
        for (int r = 0; r < 4; r++) Ofr[nt][r] = 0.f;

    const int ntiles = qt + 1;

    for (int kt = 0; kt < ntiles; kt++) {
        const int kbase = kt * 64;
        {
            const unsigned short* g0 = kgB + ((size_t)(2 * wv) * S_LEN + kbase + lane) * 8;
            gload_lds16(g0,             &Ks[(2 * wv) * 512]);
            gload_lds16(g0 + S_LEN * 8, &Ks[(2 * wv + 1) * 512]);
            const unsigned short* g1 = vgB + ((size_t)((kbase >> 3) + 2 * wv) * 64 + lane) * 8;
            gload_lds16(g1,          &Vt[(2 * wv) * 512]);
            gload_lds16(g1 + 64 * 8, &Vt[(2 * wv + 1) * 512]);
        }
        __syncthreads();

        float pex[4][4];
        #pragma unroll
        for (int sub = 0; sub < 4; sub++) {
            bf16x8 kf0 = *(const bf16x8*)&Ks[(0 * 4 + quad) * 512 + (sub * 16 + l16) * 8];
            bf16x8 kf1 = *(const bf16x8*)&Ks[(1 * 4 + quad) * 512 + (sub * 16 + l16) * 8];
            floatx4 sacc = {0.f, 0.f, 0.f, 0.f};
            sacc = __builtin_amdgcn_mfma_f32_16x16x32_bf16(kf0, qf[0], sacc, 0, 0, 0);
            sacc = __builtin_amdgcn_mfma_f32_16x16x32_bf16(kf1, qf[1], sacc, 0, 0, 0);
            #pragma unroll
            for (int r = 0; r < 4; r++) pex[sub][r] = sacc[r];
        }
        if (kt == qt) {
            const int q = qt * 64 + wv * 16 + l16;
            #pragma unroll
            for (int sub = 0; sub < 4; sub++)
                #pragma unroll
                for (int r = 0; r < 4; r++) {
                    const int key = kbase + sub * 16 + quad * 4 + r;
                    if (key > q) pex[sub][r] = -1e30f;
                }
        }
        #pragma unroll
        for (int sub = 0; sub < 4; sub++) {
            union { unsigned short s[4]; uint2 u; } pk;
            #pragma unroll
            for (int r = 0; r < 4; r++) pk.s[r] = f2bf(__expf(pex[sub][r]));
            *(uint2*)&Pw[wv][l16 * 72 + sub * 16 + quad * 4] = pk.u;
        }
        bf16x8 pf0 = *(const bf16x8*)&Pw[wv][l16 * 72 + quad * 8];
        bf16x8 pf1 = *(const bf16x8*)&Pw[wv][l16 * 72 + 32 + quad * 8];
        lfr = __builtin_amdgcn_mfma_f32_16x16x32_bf16(ones, pf0, lfr, 0, 0, 0);
        lfr = __builtin_amdgcn_mfma_f32_16x16x32_bf16(ones, pf1, lfr, 0, 0, 0);
        #pragma unroll
        for (int nt = 0; nt < 4; nt++) {
            bf16x8 v0 = *(const bf16x8*)&Vt[(0 * 4 + quad) * 512 + (nt * 16 + l16) * 8];
            bf16x8 v1 = *(const bf16x8*)&Vt[(1 * 4 + quad) * 512 + (nt * 16 + l16) * 8];
            Ofr[nt] = __builtin_amdgcn_mfma_f32_16x16x32_bf16(pf0, v0, Ofr[nt], 0, 0, 0);
            Ofr[nt] = __builtin_amdgcn_mfma_f32_16x16x32_bf16(pf1, v1, Ofr[nt], 0, 0, 0);
        }
        __syncthreads();
    }

    float linv[4];
    #pragma unroll
    for (int r = 0; r < 4; r++) {
        float lq = __shfl(lfr[0], (lane & 48) | (quad * 4 + r), 64);
        linv[r] = 1.f / lq;
    }
    #pragma unroll
    for (int nt = 0; nt < 4; nt++)
        #pragma unroll
        for (int r = 0; r < 4; r++) {
            const int s = qt * 64 + wv * 16 + quad * 4 + r;
            ao[((size_t)b * S_LEN + s) * DMODEL + h * HD + nt * 16 + l16] =
                f2bf(Ofr[nt][r] * linv[r]);
        }
}

// ---------------------------------------------------------------------------
// K3: out = ao @ w_proj^T + b_proj.  M=4096, N=1024, K=1024. fp32 out.
// Register-prefetch double buffering + swizzled conflict-free LDS. (R7)
// ---------------------------------------------------------------------------
__global__ __launch_bounds__(256) void proj_kernel(
    const unsigned short* __restrict__ a, const float* __restrict__ w,
    const float* __restrict__ bias, float* __restrict__ out)
{
    __shared__ __align__(16) unsigned short As[2048];
    __shared__ __align__(16) unsigned short Bs[2048];
    const int t = threadIdx.x;
    const int mbase = (blockIdx.x >> 4) * 64;
    const int nbase = (blockIdx.x & 15) * 64;
    const int wv = t >> 6, lane = t & 63, quad = lane >> 4, l16 = lane & 15;

    floatx4 acc[4];
    for (int i = 0; i < 4; i++)
        for (int r = 0; r < 4; r++) acc[i][r] = 0.f;

    const int srow = t >> 2;
    const int kch  = t & 3;
    const int sc8  = kch * 8;

    const int woff  = SWZ(kch, srow);
    const int aroff = SWZ(quad, wv * 16 + l16);
    int broff[4];
    #pragma unroll
    for (int nt = 0; nt < 4; nt++) broff[nt] = SWZ(quad, nt * 16 + l16);

    const unsigned short* apg = a + (size_t)(mbase + srow) * DMODEL + sc8;
    const float* bpg = w + (size_t)(nbase + srow) * DMODEL + sc8;
    short8 av8 = *(const short8*)apg;
    float4 b0 = *(const float4*)bpg;
    float4 b1 = *(const float4*)(bpg + 4);

    for (int k0 = 0; k0 < DMODEL; k0 += 32) {
        uint4 bv;
        bv.x = pkhi(b0.x, b0.y); bv.y = pkhi(b0.z, b0.w);
        bv.z = pkhi(b1.x, b1.y); bv.w = pkhi(b1.z, b1.w);
        short8 avc = av8;
        __syncthreads();
        *(short8*)&As[woff] = avc;
        *(uint4*)&Bs[woff] = bv;
        if (k0 + 32 < DMODEL) {
            av8 = *(const short8*)(apg + k0 + 32);
            const float* bp2 = bpg + k0 + 32;
            b0 = *(const float4*)bp2;
            b1 = *(const float4*)(bp2 + 4);
        }
        __syncthreads();
        bf16x8 af = *(const bf16x8*)&As[aroff];
        #pragma unroll
        for (int nt = 0; nt < 4; nt++) {
            bf16x8 bf = *(const bf16x8*)&Bs[broff[nt]];
            acc[nt] = __builtin_amdgcn_mfma_f32_16x16x32_bf16(af, bf, acc[nt], 0, 0, 0);
        }
    }

    for (int nt = 0; nt < 4; nt++) {
        const int n = nbase + nt * 16 + l16;
        const float bvv = bias[n];
        for (int r = 0; r < 4; r++) {
            const int m = mbase + wv * 16 + quad * 4 + r;
            out[(size_t)m * DMODEL + n] = acc[nt][r] + bvv;
        }
    }
}

extern "C" void kernel_launch(void* const* d_in, const int* in_sizes, int n_in,
                              void* d_out, int out_size, void* d_ws, size_t ws_size,
                              hipStream_t stream) {
    const float* x      = (const float*)d_in[0];
    const float* freqs  = (const float*)d_in[2];
    const float* w_qkv  = (const float*)d_in[3];
    const float* b_qkv  = (const float*)d_in[4];
    const float* w_proj = (const float*)d_in[5];
    const float* b_proj = (const float*)d_in[6];
    float* out = (float*)d_out;

    unsigned short* ws = (unsigned short*)d_ws;
    const size_t HSZ = (size_t)2 * NH * S_LEN * HD;
    unsigned short* qb = ws;
    unsigned short* kb = ws + HSZ;
    unsigned short* vb = ws + 2 * HSZ;
    unsigned short* ao = ws + 3 * HSZ;

    qkv_rope_kernel<<<768, 256, 0, stream>>>(x, w_qkv, b_qkv, freqs, qb, kb, vb);
    attn_kernel<<<1024, 256, 0, stream>>>(qb, kb, vb, ao);
    proj_kernel<<<1024, 256, 0, stream>>>(ao, w_proj, b_proj, out);
}

// Round 9
// 257.524 us; speedup vs baseline: 2.0345x; 2.0345x over previous
//
#include <hip/hip_runtime.h>

// Problem constants: B=2, S=2048, D=1024, H=16, HD=64
#define S_LEN 2048
#define NH 16
#define HD 64
#define DMODEL 1024

typedef __bf16 bf16x8 __attribute__((ext_vector_type(8)));
typedef float floatx4 __attribute__((ext_vector_type(4)));
typedef short short8 __attribute__((ext_vector_type(8)));

__device__ inline unsigned short f2bf(float f) {
    union { float f; unsigned u; } v; v.f = f;
    unsigned u = v.u;
    unsigned r = (u + 0x7FFFu + ((u >> 16) & 1u)) >> 16;  // RNE
    return (unsigned short)r;
}

// pack two fp32 -> bf16x2 by truncation: one v_perm_b32.
__device__ __forceinline__ unsigned pkhi(float lo, float hi) {
    union { float f; unsigned u; } a, b;
    a.f = lo; b.f = hi;
    return __builtin_amdgcn_perm(b.u, a.u, 0x07060302u);
}

__device__ __forceinline__ void gload_lds16(const void* g, void* l) {
    __builtin_amdgcn_global_load_lds(
        (const __attribute__((address_space(1))) unsigned int*)g,
        (__attribute__((address_space(3))) unsigned int*)l, 16, 0, 0);
}

// Swizzled blocked LDS layout for 64-row GEMM tiles (16B units).
#define SWZ(kch, row) (((kch) * 64 + ((row) ^ ((kch) << 2))) * 8)

// ---------------------------------------------------------------------------
// K1: qkv = x @ w_qkv^T + b_qkv, fused RoPE + scatter. (R7 skeleton: 64x64
// tile, BK=32, fp32 direct loads + register prefetch, pkhi pack, swizzled LDS.
// NOTE: 128x128 qkv variants (R5/R8) trigger a >1GB phantom-WRITE pathology —
// do not reintroduce.)
// V epilogue: Vtile transpose with b64 packed + XOR-swizzled writes
// (kills the 1.42e7-cycle 4-way bank conflicts of the b16 version).
//  q -> [bh][s][hd] row-major, PRE-SCALED by 1/sqrt(HD)=0.125 (exact)
//  k -> blocked [bh][hdblk(8)][s(2048)][8]   (RoPE applied)
//  v -> blocked [bh][sblk(256)][hd(64)][8]   (transposed via LDS tile)
// ---------------------------------------------------------------------------
__global__ __launch_bounds__(256) void qkv_rope_kernel(
    const float* __restrict__ x, const float* __restrict__ w,
    const float* __restrict__ bias, const float* __restrict__ freqs,
    unsigned short* __restrict__ qb, unsigned short* __restrict__ kb,
    unsigned short* __restrict__ vb)
{
    __shared__ __align__(16) unsigned short smem[5120];  // As(2048)+Bs(2048); Vtile(4608) in epilogue
    unsigned short* As = smem;
    unsigned short* Bs = smem + 2048;

    const int t = threadIdx.x;
    const int mbase = (blockIdx.x / 48) * 64;
    const int nbase = (blockIdx.x % 48) * 64;
    const int wv = t >> 6, lane = t & 63;
    const int quad = lane >> 4, l16 = lane & 15;

    floatx4 acc[4];
    for (int i = 0; i < 4; i++)
        for (int r = 0; r < 4; r++) acc[i][r] = 0.f;

    const int srow = t >> 2;        // 0..63
    const int kch  = t & 3;
    const int sc8  = kch * 8;

    const int woff  = SWZ(kch, srow);
    const int aroff = SWZ(quad, wv * 16 + l16);
    int broff[4];
    #pragma unroll
    for (int nt = 0; nt < 4; nt++) broff[nt] = SWZ(quad, nt * 16 + l16);

    const float* ap = x + (size_t)(mbase + srow) * DMODEL + sc8;
    const float* bp = w + (size_t)(nbase + srow) * DMODEL + sc8;
    float4 a0 = *(const float4*)ap;
    float4 a1 = *(const float4*)(ap + 4);
    float4 b0 = *(const float4*)bp;
    float4 b1 = *(const float4*)(bp + 4);

    for (int k0 = 0; k0 < DMODEL; k0 += 32) {
        uint4 av, bv;
        av.x = pkhi(a0.x, a0.y); av.y = pkhi(a0.z, a0.w);
        av.z = pkhi(a1.x, a1.y); av.w = pkhi(a1.z, a1.w);
        bv.x = pkhi(b0.x, b0.y); bv.y = pkhi(b0.z, b0.w);
        bv.z = pkhi(b1.x, b1.y); bv.w = pkhi(b1.z, b1.w);
        __syncthreads();                        // prev iter's frag reads done
        *(uint4*)&As[woff] = av;
        *(uint4*)&Bs[woff] = bv;
        if (k0 + 32 < DMODEL) {                 // register prefetch of next K-tile
            const float* ap2 = ap + k0 + 32;
            a0 = *(const float4*)ap2;
            a1 = *(const float4*)(ap2 + 4);
            const float* bp2 = bp + k0 + 32;
            b0 = *(const float4*)bp2;
            b1 = *(const float4*)(bp2 + 4);
        }
        __syncthreads();                        // staging visible
        bf16x8 af = *(const bf16x8*)&As[aroff];
        #pragma unroll
        for (int nt = 0; nt < 4; nt++) {
            bf16x8 bf = *(const bf16x8*)&Bs[broff[nt]];
            acc[nt] = __builtin_amdgcn_mfma_f32_16x16x32_bf16(af, bf, acc[nt], 0, 0, 0);
        }
    }

    // n-tile is 64 cols => single part, single head per block
    const int part = nbase >> 10;                 // 0=q 1=k 2=v
    const int h    = (nbase & 1023) >> 6;
    const int bidx = mbase >> 11;
    const int s0   = mbase & 2047;
    const size_t bh = (size_t)bidx * NH + h;

    if (part == 2) {
        // ---- V: bias, transpose 64x64 tile in LDS, blocked coalesced store.
        // Writes: one b64 per nt (4 consecutive s), unit index XOR-swizzled by
        // ((l16>>3)&1)<<1 -> breaks (l16,l16+8) bank aliasing. Reads apply the
        // matching swizzle (even swz + even s4 keeps the short8 contiguous).
        __syncthreads();                          // main-loop LDS reads done
        unsigned short* Vtile = smem;             // 64 x 72 shorts = 4608 <= 5120
        const int swzw = ((l16 >> 3) & 1) << 1;
        const int s4w  = (wv * 4 + quad) ^ swzw;
        for (int nt = 0; nt < 4; nt++) {
            const int hd = nt * 16 + l16;
            const float bvv = bias[nbase + nt * 16 + l16];
            union { unsigned short s4[4]; unsigned long long u; } pk;
            #pragma unroll
            for (int r = 0; r < 4; r++) pk.s4[r] = f2bf(acc[nt][r] + bvv);
            *(unsigned long long*)&Vtile[(hd * 18 + s4w) * 4] = pk.u;
        }
        __syncthreads();
        const int hd = t & 63, sp = t >> 6;       // sp: 0..3 -> 16 s each
        const int swzr = ((hd >> 3) & 1) << 1;
        for (int c = 0; c < 2; c++) {
            const int sl0 = sp * 16 + c * 8;
            const int sblk = (s0 + sl0) >> 3;
            short8 vv = *(const short8*)&Vtile[(hd * 18 + ((sp * 4 + c * 2) ^ swzr)) * 4];
            *(short8*)&vb[((bh * 256 + sblk) * 64 + hd) * 8] = vv;
        }
    } else {
        for (int nt = 0; nt < 4; nt++) {
            const int hd = nt * 16 + l16;
            const float bvv = bias[nbase + nt * 16 + l16];
            for (int r = 0; r < 4; r++) {
                const int s = s0 + wv * 16 + quad * 4 + r;
                float val = acc[nt][r] + bvv;
                float other = __shfl_xor(val, 1, 64);  // RoPE pair = adjacent col
                const int i = hd >> 1;
                const float f = freqs[s * 32 + i];
                const float cc = cosf(f), sn = sinf(f);
                float outv;
                if ((hd & 1) == 0) outv = val * cc - other * sn;
                else               outv = other * sn + val * cc;
                if (part == 0) {
                    outv *= 0.125f;               // fold 1/sqrt(HD), exact
                    qb[(bh * S_LEN + s) * HD + hd] = f2bf(outv);
                } else {
                    kb[((bh * 8 + (hd >> 3)) * (size_t)S_LEN + s) * 8 + (hd & 7)] = f2bf(outv);
                }
            }
        }
    }
}

// ---------------------------------------------------------------------------
// K2: causal flash attention (R4/R6 winner). No-max softmax; transposed QK;
// barrier-free P roundtrip; 1 barrier per tile; grid 1024.
// NEW: qt interleave swizzle — consecutive block groups alternate shallow/deep
// causal depth so co-resident blocks on a CU have balanced work.
// ---------------------------------------------------------------------------
__global__ __launch_bounds__(256, 4) void attn_kernel(
    const unsigned short* __restrict__ qb, const unsigned short* __restrict__ kb,
    const unsigned short* __restrict__ vbk, unsigned short* __restrict__ ao)
{
    __shared__ __align__(16) unsigned short Ks[8 * 512];
    __shared__ __align__(16) unsigned short Vt[8 * 512];
    __shared__ __align__(16) unsigned short Pw[4][16 * 72];

    const int t = threadIdx.x;
    const int wv = t >> 6, lane = t & 63, quad = lane >> 4, l16 = lane & 15;
    const int g    = blockIdx.x >> 5;
    const int qt   = (g & 1) ? (31 - (g >> 1)) : (g >> 1);   // 0,31,1,30,...
    const int bhid = blockIdx.x & 31;
    const int h = bhid & 15, b = bhid >> 4;
    const size_t bh = (size_t)b * NH + h;
    const unsigned short* qg  = qb + bh * S_LEN * HD;
    const unsigned short* kgB = kb + bh * 8 * S_LEN * 8;
    const unsigned short* vgB = vbk + bh * 256 * 64 * 8;

    bf16x8 qf[2];
    {
        const unsigned short* q0 = qg + (size_t)(qt * 64 + wv * 16 + l16) * HD;
        qf[0] = *(const bf16x8*)&q0[quad * 8];
        qf[1] = *(const bf16x8*)&q0[32 + quad * 8];
    }

    bf16x8 ones;
    {
        union { short8 s; bf16x8 v; } o;
        for (int j = 0; j < 8; j++) o.s[j] = 0x3F80;
        ones = o.v;
    }

    floatx4 lfr = {0.f, 0.f, 0.f, 0.f};
    floatx4 Ofr[4];
    for (int nt = 0; nt < 4; nt++)
        for (int r = 0; r < 4; r++) Ofr[nt][r] = 0.f;

    const int ntiles = qt + 1;

    for (int kt = 0; kt < ntiles; kt++) {
        const int kbase = kt * 64;
        {
            const unsigned short* g0 = kgB + ((size_t)(2 * wv) * S_LEN + kbase + lane) * 8;
            gload_lds16(g0,             &Ks[(2 * wv) * 512]);
            gload_lds16(g0 + S_LEN * 8, &Ks[(2 * wv + 1) * 512]);
            const unsigned short* g1 = vgB + ((size_t)((kbase >> 3) + 2 * wv) * 64 + lane) * 8;
            gload_lds16(g1,          &Vt[(2 * wv) * 512]);
            gload_lds16(g1 + 64 * 8, &Vt[(2 * wv + 1) * 512]);
        }
        __syncthreads();

        float pex[4][4];
        #pragma unroll
        for (int sub = 0; sub < 4; sub++) {
            bf16x8 kf0 = *(const bf16x8*)&Ks[(0 * 4 + quad) * 512 + (sub * 16 + l16) * 8];
            bf16x8 kf1 = *(const bf16x8*)&Ks[(1 * 4 + quad) * 512 + (sub * 16 + l16) * 8];
            floatx4 sacc = {0.f, 0.f, 0.f, 0.f};
            sacc = __builtin_amdgcn_mfma_f32_16x16x32_bf16(kf0, qf[0], sacc, 0, 0, 0);
            sacc = __builtin_amdgcn_mfma_f32_16x16x32_bf16(kf1, qf[1], sacc, 0, 0, 0);
            #pragma unroll
            for (int r = 0; r < 4; r++) pex[sub][r] = sacc[r];
        }
        if (kt == qt) {
            const int q = qt * 64 + wv * 16 + l16;
            #pragma unroll
            for (int sub = 0; sub < 4; sub++)
                #pragma unroll
                for (int r = 0; r < 4; r++) {
                    const int key = kbase + sub * 16 + quad * 4 + r;
                    if (key > q) pex[sub][r] = -1e30f;
                }
        }
        #pragma unroll
        for (int sub = 0; sub < 4; sub++) {
            union { unsigned short s[4]; uint2 u; } pk;
            #pragma unroll
            for (int r = 0; r < 4; r++) pk.s[r] = f2bf(__expf(pex[sub][r]));
            *(uint2*)&Pw[wv][l16 * 72 + sub * 16 + quad * 4] = pk.u;
        }
        bf16x8 pf0 = *(const bf16x8*)&Pw[wv][l16 * 72 + quad * 8];
        bf16x8 pf1 = *(const bf16x8*)&Pw[wv][l16 * 72 + 32 + quad * 8];
        lfr = __builtin_amdgcn_mfma_f32_16x16x32_bf16(ones, pf0, lfr, 0, 0, 0);
        lfr = __builtin_amdgcn_mfma_f32_16x16x32_bf16(ones, pf1, lfr, 0, 0, 0);
        #pragma unroll
        for (int nt = 0; nt < 4; nt++) {
            bf16x8 v0 = *(const bf16x8*)&Vt[(0 * 4 + quad) * 512 + (nt * 16 + l16) * 8];
            bf16x8 v1 = *(const bf16x8*)&Vt[(1 * 4 + quad) * 512 + (nt * 16 + l16) * 8];
            Ofr[nt] = __builtin_amdgcn_mfma_f32_16x16x32_bf16(pf0, v0, Ofr[nt], 0, 0, 0);
            Ofr[nt] = __builtin_amdgcn_mfma_f32_16x16x32_bf16(pf1, v1, Ofr[nt], 0, 0, 0);
        }
        __syncthreads();
    }

    float linv[4];
    #pragma unroll
    for (int r = 0; r < 4; r++) {
        float lq = __shfl(lfr[0], (lane & 48) | (quad * 4 + r), 64);
        linv[r] = 1.f / lq;
    }
    #pragma unroll
    for (int nt = 0; nt < 4; nt++)
        #pragma unroll
        for (int r = 0; r < 4; r++) {
            const int s = qt * 64 + wv * 16 + quad * 4 + r;
            ao[((size_t)b * S_LEN + s) * DMODEL + h * HD + nt * 16 + l16] =
                f2bf(Ofr[nt][r] * linv[r]);
        }
}

// ---------------------------------------------------------------------------
// K3: out = ao @ w_proj^T + b_proj.  M=4096, N=1024, K=1024. fp32 out.
// Register-prefetch double buffering + swizzled conflict-free LDS. (R7)
// ---------------------------------------------------------------------------
__global__ __launch_bounds__(256) void proj_kernel(
    const unsigned short* __restrict__ a, const float* __restrict__ w,
    const float* __restrict__ bias, float* __restrict__ out)
{
    __shared__ __align__(16) unsigned short As[2048];
    __shared__ __align__(16) unsigned short Bs[2048];
    const int t = threadIdx.x;
    const int mbase = (blockIdx.x >> 4) * 64;
    const int nbase = (blockIdx.x & 15) * 64;
    const int wv = t >> 6, lane = t & 63, quad = lane >> 4, l16 = lane & 15;

    floatx4 acc[4];
    for (int i = 0; i < 4; i++)
        for (int r = 0; r < 4; r++) acc[i][r] = 0.f;

    const int srow = t >> 2;
    const int kch  = t & 3;
    const int sc8  = kch * 8;

    const int woff  = SWZ(kch, srow);
    const int aroff = SWZ(quad, wv * 16 + l16);
    int broff[4];
    #pragma unroll
    for (int nt = 0; nt < 4; nt++) broff[nt] = SWZ(quad, nt * 16 + l16);

    const unsigned short* apg = a + (size_t)(mbase + srow) * DMODEL + sc8;
    const float* bpg = w + (size_t)(nbase + srow) * DMODEL + sc8;
    short8 av8 = *(const short8*)apg;
    float4 b0 = *(const float4*)bpg;
    float4 b1 = *(const float4*)(bpg + 4);

    for (int k0 = 0; k0 < DMODEL; k0 += 32) {
        uint4 bv;
        bv.x = pkhi(b0.x, b0.y); bv.y = pkhi(b0.z, b0.w);
        bv.z = pkhi(b1.x, b1.y); bv.w = pkhi(b1.z, b1.w);
        short8 avc = av8;
        __syncthreads();
        *(short8*)&As[woff] = avc;
        *(uint4*)&Bs[woff] = bv;
        if (k0 + 32 < DMODEL) {
            av8 = *(const short8*)(apg + k0 + 32);
            const float* bp2 = bpg + k0 + 32;
            b0 = *(const float4*)bp2;
            b1 = *(const float4*)(bp2 + 4);
        }
        __syncthreads();
        bf16x8 af = *(const bf16x8*)&As[aroff];
        #pragma unroll
        for (int nt = 0; nt < 4; nt++) {
            bf16x8 bf = *(const bf16x8*)&Bs[broff[nt]];
            acc[nt] = __builtin_amdgcn_mfma_f32_16x16x32_bf16(af, bf, acc[nt], 0, 0, 0);
        }
    }

    for (int nt = 0; nt < 4; nt++) {
        const int n = nbase + nt * 16 + l16;
        const float bvv = bias[n];
        for (int r = 0; r < 4; r++) {
            const int m = mbase + wv * 16 + quad * 4 + r;
            out[(size_t)m * DMODEL + n] = acc[nt][r] + bvv;
        }
    }
}

extern "C" void kernel_launch(void* const* d_in, const int* in_sizes, int n_in,
                              void* d_out, int out_size, void* d_ws, size_t ws_size,
                              hipStream_t stream) {
    const float* x      = (const float*)d_in[0];
    const float* freqs  = (const float*)d_in[2];
    const float* w_qkv  = (const float*)d_in[3];
    const float* b_qkv  = (const float*)d_in[4];
    const float* w_proj = (const float*)d_in[5];
    const float* b_proj = (const float*)d_in[6];
    float* out = (float*)d_out;

    unsigned short* ws = (unsigned short*)d_ws;
    const size_t HSZ = (size_t)2 * NH * S_LEN * HD;
    unsigned short* qb = ws;
    unsigned short* kb = ws + HSZ;
    unsigned short* vb = ws + 2 * HSZ;
    unsigned short* ao = ws + 3 * HSZ;

    qkv_rope_kernel<<<3072, 256, 0, stream>>>(x, w_qkv, b_qkv, freqs, qb, kb, vb);
    attn_kernel<<<1024, 256, 0, stream>>>(qb, kb, vb, ao);
    proj_kernel<<<1024, 256, 0, stream>>>(ao, w_proj, b_proj, out);
}